// Round 3
// 104.700 us; speedup vs baseline: 1.0633x; 1.0633x over previous
//
#include <hip/hip_runtime.h>
#include <math.h>

#define NVARS 14
#define EDIM 32
#define VMIX 3
#define KSTATES 16384
#define BATCH 32

// bf16 swizzled-fragment regions in ws (byte offsets):
#define WS_DSWZ_B  32768                       // [V][18][64][8] bf16 = 55296 B
#define WS_W2SWZ_B (WS_DSWZ_B + 55296)         // [V][9][26][64][8] = 718848 B
#define WS_W3SWZ_B (WS_W2SWZ_B + 718848)       // [V][13][4][64][8] = 79872 B

// LDS strides (shorts). H1S: 148dw%32=20 -> spread banks for b128 (ok).
// H2S: 420 shorts = 210dw, 210%32=18 -> distinct banks across 16 rows;
// 64*420*2=53760B keeps total block LDS <= 54613 so 3 blocks/CU fit
// (single grid round: 768 blocks = 3/CU x 256 CU resident at once).
// NOTE: do NOT raise __launch_bounds__ min-waves beyond 4 — (512,6) forced
// VGPR=40 and spilled (R5: WRITE_SIZE 24->83MB, main 33->95us).
#define H1S 296
#define H2S 420
#define MS  72

typedef __attribute__((ext_vector_type(8))) short bf16x8;
typedef __attribute__((ext_vector_type(4))) float f32x4;
typedef __attribute__((ext_vector_type(2))) unsigned int u32x2;

static __device__ inline unsigned short f2bf(float f) {
    unsigned u = __float_as_uint(f);
    u += 0x7FFFu + ((u >> 16) & 1u);   // RNE
    return (unsigned short)(u >> 16);
}
// packed RNE f32x2 -> bf16x2 (lo in bits[15:0]); bit-identical to f2bf for
// finite values, 1 VALU instr instead of ~10.
static __device__ inline unsigned cvtpk(float lo, float hi) {
    unsigned r;
    asm("v_cvt_pk_bf16_f32 %0, %1, %2" : "=v"(r) : "v"(lo), "v"(hi));
    return r;
}
static __device__ inline float elu(float x) {
    return x > 0.f ? x : (__expf(x) - 1.f);
}

// ---------------- pre (single kernel, role-split grid) ----------------
// blocks [0,172): W2eff/W3eff fragment swizzles (54912 groups)
// blocks [172,214): Dmat delta rows k<14 (block = (v,k)); recomputes its T cols
// blocks [214,217): Dmat base row k=14 + zero-fill k>=15 (block = v)
// NOTE: the swizzled layout (elem j of frag (nt,l) = M[k=(l>>4)*8+j][n=nt*16+(l&15)])
// serves BOTH as an MFMA B-fragment (col=n) and as an A-fragment (row=n) —
// the 16x16x32 A/B lane layouts are identical. main now consumes these as A.
__global__ __launch_bounds__(320) void pre_kernel(const float* __restrict__ emb,
                                                  const float* __restrict__ lin_w,
                                                  const float* __restrict__ lin_b,
                                                  const float* __restrict__ b1,
                                                  const float* __restrict__ w1,
                                                  const float* __restrict__ w2,
                                                  const float* __restrict__ w3,
                                                  float* __restrict__ ws) {
    int blk = blockIdx.x;
    int tid = threadIdx.x;
    char* wsb = (char*)ws;
    unsigned short* dmat = (unsigned short*)(wsb + WS_DSWZ_B);
    __shared__ float sP[128];
    __shared__ float sQ[64];

    if (blk < 172) {
        int g2 = blk * 320 + tid;
        if (g2 >= 54912) return;
        bf16x8 o8;
        if (g2 < 44928) {                  // W2eff
            int h = g2;
            int v = h / 14976;
            int r = h % 14976;
            int kt = r / 1664;
            int r2 = r % 1664;
            int nt = r2 / 64, l = r2 % 64;
            int n = nt * 16 + (l & 15);
            int kbase = kt * 32 + ((l >> 4) & 3) * 8;
            #pragma unroll
            for (int j = 0; j < 8; ++j) {
                int k = kbase + j;         // k < 288
                float val = 0.f;
                if (n < 400) {
                    int i = k / 9, p = k % 9;
                    int py = p / 3, px = p % 3;
                    int o = n / 25, q = n % 25;
                    int qy = q / 5, qx = q % 5;
                    int ty = qy - py, tx = qx - px;
                    if (ty >= 0 && ty < 3 && tx >= 0 && tx < 3)
                        val = w2[((size_t)(v * 32 + i) * 16 + o) * 9 + ty * 3 + tx];
                }
                o8[j] = (short)f2bf(val);
            }
        } else {                           // W3eff
            int h = g2 - 44928;
            int v = h / 3328;
            int r = h % 3328;
            int kt = r / 256;
            int r2 = r % 256;
            int nt = r2 / 64, l = r2 % 64;
            int n = nt * 16 + (l & 15);    // output pixel 0..48 (else pad)
            int kbase = kt * 32 + ((l >> 4) & 3) * 8;
            #pragma unroll
            for (int j = 0; j < 8; ++j) {
                int k = kbase + j;
                float val = 0.f;
                if (k < 400 && n < 49) {
                    int o = k / 25, q = k % 25;
                    int qy = q / 5, qx = q % 5;
                    int py = n / 7, px = n % 7;
                    int ty = py - qy, tx = px - qx;
                    if (ty >= 0 && ty < 3 && tx >= 0 && tx < 3)
                        val = w3[(size_t)(v * 16 + o) * 9 + ty * 3 + tx];
                }
                o8[j] = (short)f2bf(val);
            }
        }
        *(bf16x8*)(wsb + WS_DSWZ_B + ((size_t)g2 + 3456) * 16) = o8;
        return;
    }

    if (blk < 214) {                       // delta row (v,k)
        int b = blk - 172;
        int v = b / 14;
        int k = b % 14;
        if (tid < 128) {                   // T columns: sP[c*64+i]
            int c = tid >> 6, i = tid & 63;
            const float* e = emb + (k * 2 + c) * EDIM;
            const float* lw = lin_w + ((size_t)v * 448 + k * 32) * 64 + i;
            float a0 = 0.f, a1 = 0.f;
            #pragma unroll
            for (int e2 = 0; e2 < 32; e2 += 2) {
                a0 = fmaf(e[e2], lw[e2 * 64], a0);
                a1 = fmaf(e[e2 + 1], lw[(e2 + 1) * 64], a1);
            }
            sP[tid] = a0 + a1;
        }
        __syncthreads();
        if (tid < 64) sQ[tid] = sP[64 + tid] - sP[tid];
        __syncthreads();
        if (tid < 288) {
            int n = tid;
            const float* w1v = w1 + (size_t)v * 64 * 288 + n;
            float a0 = 0.f, a1 = 0.f;
            #pragma unroll
            for (int i = 0; i < 64; i += 2) {
                a0 = fmaf(sQ[i], w1v[i * 288], a0);
                a1 = fmaf(sQ[i + 1], w1v[(i + 1) * 288], a1);
            }
            int nt = n >> 4;
            int l = (n & 15) | ((k >> 3) << 4);
            dmat[((size_t)(v * 18 + nt) * 64 + l) * 8 + (k & 7)] = f2bf(a0 + a1);
        }
        return;
    }

    {                                      // base row + zero-fill, block = v
        int v = blk - 214;
        // zero all k>=15 slots of this v's Dmat region
        for (int t = tid; t < 9216; t += 320) {
            int j3 = t & 7;
            int l = (t >> 3) & 63;
            int k2 = ((l >> 4) << 3) | j3;
            if (k2 >= 15) dmat[(size_t)v * 9216 + t] = 0;
        }
        if (tid < 128) {                   // partial sums of c=0 T columns
            int half = tid >> 6, i = tid & 63;
            float a0 = 0.f, a1 = 0.f;
            for (int n2 = half * 7; n2 < half * 7 + 7; ++n2) {
                const float* e = emb + (n2 * 2) * EDIM;
                const float* lw = lin_w + ((size_t)v * 448 + n2 * 32) * 64 + i;
                #pragma unroll
                for (int e2 = 0; e2 < 32; e2 += 2) {
                    a0 = fmaf(e[e2], lw[e2 * 64], a0);
                    a1 = fmaf(e[e2 + 1], lw[(e2 + 1) * 64], a1);
                }
            }
            sP[tid] = a0 + a1;
        }
        __syncthreads();
        if (tid < 64) sQ[tid] = lin_b[v * 64 + tid] + sP[tid] + sP[64 + tid];
        __syncthreads();
        if (tid < 288) {
            int n = tid;
            const float* w1v = w1 + (size_t)v * 64 * 288 + n;
            float a0 = b1[v * 32 + n / 9], a1 = 0.f;
            #pragma unroll
            for (int i = 0; i < 64; i += 2) {
                a0 = fmaf(sQ[i], w1v[i * 288], a0);
                a1 = fmaf(sQ[i + 1], w1v[(i + 1) * 288], a1);
            }
            int nt = n >> 4;
            int l = (n & 15) | 16;         // k=14 -> quadK 1, j 6
            dmat[((size_t)(v * 18 + nt) * 64 + l) * 8 + 6] = f2bf(a0 + a1);
        }
    }
}

// ---------------- main: MFMA decoder + distance (512 threads, 8 waves) ----------------
// R6 change: all GEMMs compute the TRANSPOSED output (operand swap: the ws
// swizzled fragment is the A operand, the LDS [row][k] b128 read is the B
// operand). C/D layout (col=lane&15, row=(lane>>4)*4+reg) then puts each
// lane's 4 regs on 4 CONSECUTIVE LDS shorts of the same row -> epilogues are
// 2x v_cvt_pk_bf16_f32 + 1x ds_write_b64 instead of 4x (f2bf + ds_write_b16).
// Read paths (P1/P3/P4 b128 LDS reads) are unchanged.
__global__ __launch_bounds__(512, 4) void emission_main(const float* __restrict__ x,
                                                        const float* __restrict__ b2,
                                                        const float* __restrict__ b3p,
                                                        const float* __restrict__ ws,
                                                        float* __restrict__ out) {
    int bid = blockIdx.x;
    // XCD swizzle: v-trio for a chunk shares bid%8 and is temporally close.
    int group = bid / 24;
    int j24 = bid % 24;
    int v = j24 >> 3;
    int chunk = group * 8 + (j24 & 7);    // states [chunk*64, chunk*64+64)
    int tid = threadIdx.x;
    int w = tid >> 6;           // wave 0..7
    int l = tid & 63;
    int quad = l >> 4;
    int lc = l & 15;
    const char* wsb = (const char*)ws;

    // union: sH1 (64 x H1S shorts) -> sH2 (64 x H2S) -> sM (64 x MS)
    __shared__ __align__(16) unsigned short uni[64 * H2S];
    __shared__ float sMsq[64];
    __shared__ float sXsq[32];
    __shared__ float sB2[16];

    // ---------- P0: small LDS prep ----------
    if (tid < 16) sB2[tid] = b2[v * 16 + tid];
    if (tid < 64) sMsq[tid] = 0.f;
    if (tid >= 64 && tid < 96) {
        int b = tid - 64;
        const float* xb = x + (size_t)(b * 3 + v) * 49;
        float s = 0.f;
        #pragma unroll
        for (int p = 0; p < 49; ++p) s = fmaf(xb[p], xb[p], s);
        sXsq[b] = s;
    }

    int mt0 = w & 3;            // this wave's s-tile for P0b/P3
    // ---------- P0b: H1[s][n] = ELU(bits @ Dmat); wave (mt0, nh = w>>2) ----------
    // swapped: D = mfma(DmatFrag, bits) -> rows = n (4 consecutive per lane).
    {
        int nh = w >> 2;
        int sg = chunk * 64 + mt0 * 16 + lc;
        bf16x8 abits;                      // B operand: col s=lc, k=quad*8+j
        #pragma unroll
        for (int j = 0; j < 8; ++j) {
            int k = quad * 8 + j;
            unsigned short u = 0;
            if (k < 14) u = ((sg >> (13 - k)) & 1) ? 0x3F80 : 0;
            else if (k == 14) u = 0x3F80;
            abits[j] = (short)u;
        }
        const bf16x8* dsw = (const bf16x8*)(wsb + WS_DSWZ_B) + (size_t)v * 18 * 64;
        #pragma unroll 3
        for (int i = 0; i < 9; ++i) {
            int nt = nh * 9 + i;
            bf16x8 afrag = dsw[nt * 64 + l];
            f32x4 d = {0.f, 0.f, 0.f, 0.f};
            d = __builtin_amdgcn_mfma_f32_16x16x32_bf16(afrag, abits, d, 0, 0, 0);
            // n = nt*16 + quad*4 + r, s = mt0*16 + lc
            unsigned lo = cvtpk(elu(d[0]), elu(d[1]));
            unsigned hi = cvtpk(elu(d[2]), elu(d[3]));
            *(u32x2*)&uni[(mt0 * 16 + lc) * H1S + nt * 16 + quad * 4] = (u32x2){lo, hi};
        }
    }
    __syncthreads();

    // ---------- P1: conv2 GEMM  H2pre^T: D[n][s] = W2eff^T-frag @ H1[s][k] ----------
    // n-tile 25 (cols 400-415) is identically zero -> skipped; 25 real tiles:
    // wave 0 gets {0..3}, wave w>=1 gets {1+3w .. 3+3w} (max 24).
    int ncnt = (w == 0) ? 4 : 3;
    int n0 = (w == 0) ? 0 : 1 + 3 * w;
    f32x4 acc[4][4];
    #pragma unroll
    for (int mt = 0; mt < 4; ++mt)
        #pragma unroll
        for (int j = 0; j < 4; ++j)
            acc[mt][j] = (f32x4){0.f, 0.f, 0.f, 0.f};
    {
        const bf16x8* w2f = (const bf16x8*)(wsb + WS_W2SWZ_B) + (size_t)v * 9 * 26 * 64;
        for (int kt = 0; kt < 9; ++kt) {
            bf16x8 af[4];                  // A: W2eff fragments (global/L2 first)
            #pragma unroll
            for (int j = 0; j < 4; ++j)
                if (j < ncnt) af[j] = w2f[(kt * 26 + n0 + j) * 64 + l];
            bf16x8 hb[4];                  // B: H1 as [k][s] (LDS b128, unchanged addr)
            #pragma unroll
            for (int mt = 0; mt < 4; ++mt)
                hb[mt] = *(const bf16x8*)&uni[(mt * 16 + lc) * H1S + kt * 32 + quad * 8];
            #pragma unroll
            for (int j = 0; j < 4; ++j)
                if (j < ncnt)
                    #pragma unroll
                    for (int mt = 0; mt < 4; ++mt)
                        acc[mt][j] = __builtin_amdgcn_mfma_f32_16x16x32_bf16(af[j], hb[mt], acc[mt][j], 0, 0, 0);
        }
    }
    __syncthreads();   // all H1 reads done before uni is reused as sH2

    // X A-frags for P4 (this wave's b-tile bt = w>>2), built in registers
    bf16x8 xf[2];
    {
        int bt = w >> 2;
        #pragma unroll
        for (int kt = 0; kt < 2; ++kt) {
            int b = bt * 16 + lc;
            const float* xb = x + (size_t)(b * 3 + v) * 49;
            union { bf16x8 h; unsigned u[4]; } xu;
            #pragma unroll
            for (int jj = 0; jj < 4; ++jj) {
                int p0 = kt * 32 + quad * 8 + jj * 2;
                float f0 = (p0 < 49) ? xb[p0] : 0.f;
                float f1 = (p0 + 1 < 49) ? xb[p0 + 1] : 0.f;
                xu.u[jj] = cvtpk(f0, f1);
            }
            xf[kt] = xu.h;
        }
    }

    // ---------- P2: bias + ELU + packed bf16 -> sH2[s][H2S] (b64 stores) ----------
    #pragma unroll
    for (int j = 0; j < 4; ++j) {
        if (j < ncnt) {
            #pragma unroll
            for (int mt = 0; mt < 4; ++mt) {
                float vv[4];
                #pragma unroll
                for (int r = 0; r < 4; ++r) {
                    int n = (n0 + j) * 16 + quad * 4 + r;   // n <= 399 always
                    vv[r] = elu(acc[mt][j][r] + sB2[n / 25]);
                }
                unsigned lo = cvtpk(vv[0], vv[1]);
                unsigned hi = cvtpk(vv[2], vv[3]);
                *(u32x2*)&uni[(mt * 16 + lc) * H2S + (n0 + j) * 16 + quad * 4] = (u32x2){lo, hi};
            }
        }
    }
    // wave 1: zero k-cols 400..415 of every s-row so P3's B reads are clean
    if (w == 1) {
        unsigned short* rowp = &uni[l * H2S + 400];
        *(u32x2*)&rowp[0]  = (u32x2){0u, 0u};
        *(u32x2*)&rowp[4]  = (u32x2){0u, 0u};
        *(u32x2*)&rowp[8]  = (u32x2){0u, 0u};
        *(u32x2*)&rowp[12] = (u32x2){0u, 0u};
    }
    __syncthreads();

    // ---------- P3: conv3 GEMM  m^T: D[p][s] = W3eff-frag @ H2[s][k] ----------
    // wave: (mt0 = w&3 s-tile, p-tiles {ph, ph+2}, ph = w>>2)
    int ph = w >> 2;
    f32x4 acc2[2];
    acc2[0] = (f32x4){0.f, 0.f, 0.f, 0.f};
    acc2[1] = (f32x4){0.f, 0.f, 0.f, 0.f};
    {
        const bf16x8* w3f = (const bf16x8*)(wsb + WS_W3SWZ_B) + (size_t)v * 13 * 4 * 64;
        for (int kt = 0; kt < 13; ++kt) {
            bf16x8 hb = *(const bf16x8*)&uni[(mt0 * 16 + lc) * H2S + kt * 32 + quad * 8];
            #pragma unroll
            for (int c = 0; c < 2; ++c) {
                int pt = ph + 2 * c;
                bf16x8 af = w3f[(kt * 4 + pt) * 64 + l];
                acc2[c] = __builtin_amdgcn_mfma_f32_16x16x32_bf16(af, hb, acc2[c], 0, 0, 0);
            }
        }
    }
    // epilogue: means (p in rows now), ||m||^2 via quad-reduce
    float b3v = b3p[v];
    float mv[2][4];
    #pragma unroll
    for (int c = 0; c < 2; ++c) {
        #pragma unroll
        for (int r = 0; r < 4; ++r) {
            int p = (ph + 2 * c) * 16 + quad * 4 + r;
            mv[c][r] = (p < 49) ? (acc2[c][r] + b3v) : 0.f;
        }
    }
    {
        float sq = 0.f;
        #pragma unroll
        for (int c = 0; c < 2; ++c)
            #pragma unroll
            for (int r = 0; r < 4; ++r)
                sq = fmaf(mv[c][r], mv[c][r], sq);
        sq += __shfl_xor(sq, 16, 64);
        sq += __shfl_xor(sq, 32, 64);
        if (l < 16) atomicAdd(&sMsq[mt0 * 16 + lc], sq);   // 2 waves per s-tile
    }
    __syncthreads();   // conv3 reads of uni done before reuse as sM
    #pragma unroll
    for (int c = 0; c < 2; ++c) {
        unsigned lo = cvtpk(mv[c][0], mv[c][1]);
        unsigned hi = cvtpk(mv[c][2], mv[c][3]);
        *(u32x2*)&uni[(mt0 * 16 + lc) * MS + (ph + 2 * c) * 16 + quad * 4] = (u32x2){lo, hi};
    }
    __syncthreads();

    // ---------- P4: cross = X(32x64p) @ M^T, wave: (st = w&3, bt = w>>2) ----------
    {
        int st = w & 3, bt = w >> 2;
        f32x4 acc3 = {0.f, 0.f, 0.f, 0.f};
        #pragma unroll
        for (int kt = 0; kt < 2; ++kt) {
            bf16x8 bm = *(const bf16x8*)&uni[(st * 16 + lc) * MS + kt * 32 + quad * 8];
            acc3 = __builtin_amdgcn_mfma_f32_16x16x32_bf16(xf[kt], bm, acc3, 0, 0, 0);
        }
        int s = st * 16 + lc;
        float msq = sMsq[s];
        size_t kidx = (size_t)(chunk * 64 + s) * 3 + v;
        #pragma unroll
        for (int r = 0; r < 4; ++r) {
            int b = bt * 16 + quad * 4 + r;
            out[(size_t)b * (KSTATES * 3) + kidx] = acc3[r] - 0.5f * (msq + sXsq[b]);
        }
    }
}

extern "C" void kernel_launch(void* const* d_in, const int* in_sizes, int n_in,
                              void* d_out, int out_size, void* d_ws, size_t ws_size,
                              hipStream_t stream) {
    const float* x    = (const float*)d_in[0];   // (32,3,7,7)
    const float* emb  = (const float*)d_in[1];   // (14,2,32)
    const float* linw = (const float*)d_in[2];   // (3,448,64)
    const float* linb = (const float*)d_in[3];   // (3,64)
    const float* w1   = (const float*)d_in[4];   // (3,64,32,3,3)
    const float* b1   = (const float*)d_in[5];   // (3,32)
    const float* w2   = (const float*)d_in[6];   // (3,32,16,3,3)
    const float* b2   = (const float*)d_in[7];   // (3,16)
    const float* w3   = (const float*)d_in[8];   // (3,16,1,3,3)
    const float* b3   = (const float*)d_in[9];   // (3,1)
    float* out = (float*)d_out;
    float* ws = (float*)d_ws;

    pre_kernel<<<217, 320, 0, stream>>>(emb, linw, linb, b1, w1, w2, w3, ws);
    emission_main<<<768, 512, 0, stream>>>(x, b2, b3, ws, out);
}

// Round 7
// 103.018 us; speedup vs baseline: 1.0806x; 1.0163x over previous
//
#include <hip/hip_runtime.h>
#include <math.h>

#define NVARS 14
#define EDIM 32
#define VMIX 3
#define KSTATES 16384
#define BATCH 32

// bf16 swizzled-fragment regions in ws (byte offsets):
// R7: W2eff (719KB dense, 36% nonzero) replaced by W2c: the 9 distinct
// 16(o)x32(i) weight blocks w2[i][o][ty,tx] as MFMA A-fragments (27KB).
// H1 columns permuted tap-major (n' = p*32+i), H2 columns pixel-major
// (n' = q*16+o) so each conv2 tap is one contiguous K=32 step.
#define WS_DSWZ_B  32768                       // [V][18][64][8] bf16 = 55296 B
#define WS_W2C_B   (WS_DSWZ_B + 55296)         // [V][9][64][8]  = 27648 B
#define WS_W3SWZ_B (WS_W2C_B + 27648)          // [V][13][4][64][8] = 79872 B

// LDS strides (shorts). H1S: 148dw%32=20 -> spread banks for b128 (ok).
// H2S: 420 shorts = 210dw, 210%32=18 -> distinct banks across 16 rows;
// 64*420*2=53760B keeps total block LDS <= 54613 so 3 blocks/CU fit
// (single grid round: 768 blocks = 3/CU x 256 CU resident at once).
// NOTE: do NOT raise __launch_bounds__ min-waves beyond 4 — (512,6) forced
// VGPR=40 and spilled (R5: WRITE_SIZE 24->83MB, main 33->95us).
#define H1S 296
#define H2S 420
#define MS  72

typedef __attribute__((ext_vector_type(8))) short bf16x8;
typedef __attribute__((ext_vector_type(4))) float f32x4;
typedef __attribute__((ext_vector_type(2))) unsigned int u32x2;

static __device__ inline unsigned short f2bf(float f) {
    unsigned u = __float_as_uint(f);
    u += 0x7FFFu + ((u >> 16) & 1u);   // RNE
    return (unsigned short)(u >> 16);
}
// packed RNE f32x2 -> bf16x2 (lo in bits[15:0]); bit-identical to f2bf for
// finite values, 1 VALU instr instead of ~10.
static __device__ inline unsigned cvtpk(float lo, float hi) {
    unsigned r;
    asm("v_cvt_pk_bf16_f32 %0, %1, %2" : "=v"(r) : "v"(lo), "v"(hi));
    return r;
}
static __device__ inline float elu(float x) {
    return x > 0.f ? x : (__expf(x) - 1.f);
}

// Per-wave conv2 output-tile assignment (q = qy*5+qx, 0..24), balanced by
// tap count vp(q) = vy[qy]*vy[qx], vy=[1,2,3,2,1], Sigma vp = 81 K-steps.
// Max 4 tiles/wave (acc register cap) and 8..11 K-steps/wave.
// bytes LSB..MSB = q0,q1,q2,q3; 0xFF = empty slot.
static __device__ const unsigned QPACK[8] = {
    0xFF04000Cu,  // w0: 12,0,4      (9+1+1 = 11)
    0xFF140607u,  // w1: 7,6,20      (6+4+1 = 11)
    0xFF18080Bu,  // w2: 11,8,24     (6+4+1 = 11)
    0xFFFF100Du,  // w3: 13,16       (6+4   = 10)
    0xFFFF1211u,  // w4: 17,18       (6+4   = 10)
    0x03010E0Au,  // w5: 10,14,1,3   (3+3+2+2 = 10)
    0x09051602u,  // w6: 2,22,5,9    (3+3+2+2 = 10)
    0x1715130Fu   // w7: 15,19,21,23 (2+2+2+2 = 8)
};

// ---------------- pre (single kernel, role-split grid) ----------------
// blocks [0,37): W3eff fragment swizzle (9984 groups, k' = q*16+o permuted)
//                + W2c A-fragment gather (1728 groups)
// blocks [37,79): Dmat delta rows k<14 (block = (v,k)); tap-major columns
// blocks [79,82): Dmat base row k=14 + zero-fill k>=15 (block = v)
// NOTE: the swizzled layout (elem j of frag (nt,l) = M[k=(l>>4)*8+j][n=nt*16+(l&15)])
// serves BOTH as an MFMA B-fragment (col=n) and as an A-fragment (row=n) —
// the 16x16x32 A/B lane layouts are identical. main consumes these as A.
__global__ __launch_bounds__(320) void pre_kernel(const float* __restrict__ emb,
                                                  const float* __restrict__ lin_w,
                                                  const float* __restrict__ lin_b,
                                                  const float* __restrict__ b1,
                                                  const float* __restrict__ w1,
                                                  const float* __restrict__ w2,
                                                  const float* __restrict__ w3,
                                                  float* __restrict__ ws) {
    int blk = blockIdx.x;
    int tid = threadIdx.x;
    char* wsb = (char*)ws;
    unsigned short* dmat = (unsigned short*)(wsb + WS_DSWZ_B);
    __shared__ float sP[128];
    __shared__ float sQ[64];

    if (blk < 37) {
        int g2 = blk * 320 + tid;
        if (g2 < 9984) {                   // W3eff, permuted K: k' = q*16+o
            int v = g2 / 3328;
            int r = g2 % 3328;
            int kt = r / 256;
            int r2 = r % 256;
            int nt = r2 / 64, l = r2 % 64;
            int n = nt * 16 + (l & 15);    // output pixel 0..48 (else pad)
            int kbase = kt * 32 + ((l >> 4) & 3) * 8;
            bf16x8 o8;
            #pragma unroll
            for (int j = 0; j < 8; ++j) {
                int k = kbase + j;
                float val = 0.f;
                if (k < 400 && n < 49) {
                    int q = k >> 4, o = k & 15;     // k' = q*16 + o
                    int qy = q / 5, qx = q % 5;
                    int py = n / 7, px = n % 7;
                    int ty = py - qy, tx = px - qx;
                    if (ty >= 0 && ty < 3 && tx >= 0 && tx < 3)
                        val = w3[(size_t)(v * 16 + o) * 9 + ty * 3 + tx];
                }
                o8[j] = (short)f2bf(val);
            }
            *(bf16x8*)(wsb + WS_W3SWZ_B + (size_t)g2 * 16) = o8;
        } else if (g2 < 11712) {           // W2c: A[o=l&15][i=(l>>4)*8+j] = w2[i][o][t]
            int g = g2 - 9984;
            int v = g / 576;
            int r = g % 576;
            int t = r / 64, l = r % 64;
            int o = l & 15;
            int ibase = ((l >> 4) & 3) * 8;
            bf16x8 o8;
            #pragma unroll
            for (int j = 0; j < 8; ++j) {
                int i = ibase + j;
                o8[j] = (short)f2bf(w2[((size_t)(v * 32 + i) * 16 + o) * 9 + t]);
            }
            *(bf16x8*)(wsb + WS_W2C_B + (size_t)g * 16) = o8;
        }
        return;
    }

    if (blk < 79) {                        // delta row (v,k)
        int b = blk - 37;
        int v = b / 14;
        int k = b % 14;
        if (tid < 128) {                   // T columns: sP[c*64+i]
            int c = tid >> 6, i = tid & 63;
            const float* e = emb + (k * 2 + c) * EDIM;
            const float* lw = lin_w + ((size_t)v * 448 + k * 32) * 64 + i;
            float a0 = 0.f, a1 = 0.f;
            #pragma unroll
            for (int e2 = 0; e2 < 32; e2 += 2) {
                a0 = fmaf(e[e2], lw[e2 * 64], a0);
                a1 = fmaf(e[e2 + 1], lw[(e2 + 1) * 64], a1);
            }
            sP[tid] = a0 + a1;
        }
        __syncthreads();
        if (tid < 64) sQ[tid] = sP[64 + tid] - sP[tid];
        __syncthreads();
        if (tid < 288) {
            int n = tid;
            const float* w1v = w1 + (size_t)v * 64 * 288 + n;
            float a0 = 0.f, a1 = 0.f;
            #pragma unroll
            for (int i = 0; i < 64; i += 2) {
                a0 = fmaf(sQ[i], w1v[i * 288], a0);
                a1 = fmaf(sQ[i + 1], w1v[(i + 1) * 288], a1);
            }
            // tap-major column permutation: n = i*9+p -> n2 = p*32+i
            int ci = n / 9, p = n % 9;
            int n2 = p * 32 + ci;
            int nt = n2 >> 4;
            int l = (n2 & 15) | ((k >> 3) << 4);
            dmat[((size_t)(v * 18 + nt) * 64 + l) * 8 + (k & 7)] = f2bf(a0 + a1);
        }
        return;
    }

    {                                      // base row + zero-fill, block = v
        int v = blk - 79;
        // zero all k>=15 slots of this v's Dmat region
        for (int t = tid; t < 9216; t += 320) {
            int j3 = t & 7;
            int l = (t >> 3) & 63;
            int k2 = ((l >> 4) << 3) | j3;
            if (k2 >= 15) dmat[(size_t)v * 9216 + t] = 0;
        }
        if (tid < 128) {                   // partial sums of c=0 T columns
            int half = tid >> 6, i = tid & 63;
            float a0 = 0.f, a1 = 0.f;
            for (int n2 = half * 7; n2 < half * 7 + 7; ++n2) {
                const float* e = emb + (n2 * 2) * EDIM;
                const float* lw = lin_w + ((size_t)v * 448 + n2 * 32) * 64 + i;
                #pragma unroll
                for (int e2 = 0; e2 < 32; e2 += 2) {
                    a0 = fmaf(e[e2], lw[e2 * 64], a0);
                    a1 = fmaf(e[e2 + 1], lw[(e2 + 1) * 64], a1);
                }
            }
            sP[tid] = a0 + a1;
        }
        __syncthreads();
        if (tid < 64) sQ[tid] = lin_b[v * 64 + tid] + sP[tid] + sP[64 + tid];
        __syncthreads();
        if (tid < 288) {
            int n = tid;
            const float* w1v = w1 + (size_t)v * 64 * 288 + n;
            float a0 = b1[v * 32 + n / 9], a1 = 0.f;
            #pragma unroll
            for (int i = 0; i < 64; i += 2) {
                a0 = fmaf(sQ[i], w1v[i * 288], a0);
                a1 = fmaf(sQ[i + 1], w1v[(i + 1) * 288], a1);
            }
            int ci = n / 9, p = n % 9;
            int n2 = p * 32 + ci;
            int nt = n2 >> 4;
            int l = (n2 & 15) | 16;        // k=14 -> quadK 1, j 6
            dmat[((size_t)(v * 18 + nt) * 64 + l) * 8 + 6] = f2bf(a0 + a1);
        }
    }
}

// ---------------- main: MFMA decoder + distance (512 threads, 8 waves) ----------------
// All GEMMs compute the TRANSPOSED output (operand swap: weight fragment = A,
// LDS [row][k] b128 read = B). C/D layout (col=lane&15, row=(lane>>4)*4+reg)
// puts each lane's 4 regs on 4 consecutive LDS shorts -> epilogues are
// 2x v_cvt_pk_bf16_f32 + 1x ds_write_b64.
// R7: P1 is conv-structured — per output pixel q only its vp(q) valid taps
// (81 K-steps total vs 225 dense), A-operands from the 9-entry W2c table.
__global__ __launch_bounds__(512, 4) void emission_main(const float* __restrict__ x,
                                                        const float* __restrict__ b2,
                                                        const float* __restrict__ b3p,
                                                        const float* __restrict__ ws,
                                                        float* __restrict__ out) {
    int bid = blockIdx.x;
    // XCD swizzle: v-trio for a chunk shares bid%8 and is temporally close.
    int group = bid / 24;
    int j24 = bid % 24;
    int v = j24 >> 3;
    int chunk = group * 8 + (j24 & 7);    // states [chunk*64, chunk*64+64)
    int tid = threadIdx.x;
    int w = tid >> 6;           // wave 0..7
    int l = tid & 63;
    int quad = l >> 4;
    int lc = l & 15;
    const char* wsb = (const char*)ws;

    // union: sH1 (64 x H1S shorts) -> sH2 (64 x H2S) -> sM (64 x MS)
    __shared__ __align__(16) unsigned short uni[64 * H2S];
    __shared__ float sMsq[64];
    __shared__ float sXsq[32];
    __shared__ float sB2[16];

    // ---------- P0: small LDS prep ----------
    if (tid < 16) sB2[tid] = b2[v * 16 + tid];
    if (tid < 64) sMsq[tid] = 0.f;
    if (tid >= 64 && tid < 96) {
        int b = tid - 64;
        const float* xb = x + (size_t)(b * 3 + v) * 49;
        float s = 0.f;
        #pragma unroll
        for (int p = 0; p < 49; ++p) s = fmaf(xb[p], xb[p], s);
        sXsq[b] = s;
    }

    int mt0 = w & 3;            // this wave's s-tile for P0b/P3
    // ---------- P0b: H1'[s][n'] = ELU(bits @ Dmat); wave (mt0, nh = w>>2) ----------
    // swapped: D = mfma(DmatFrag, bits) -> rows = n' (4 consecutive per lane).
    // Columns are tap-major (n' = p*32+i) via pre's Dmat permutation.
    {
        int nh = w >> 2;
        int sg = chunk * 64 + mt0 * 16 + lc;
        bf16x8 abits;                      // B operand: col s=lc, k=quad*8+j
        #pragma unroll
        for (int j = 0; j < 8; ++j) {
            int k = quad * 8 + j;
            unsigned short u = 0;
            if (k < 14) u = ((sg >> (13 - k)) & 1) ? 0x3F80 : 0;
            else if (k == 14) u = 0x3F80;
            abits[j] = (short)u;
        }
        const bf16x8* dsw = (const bf16x8*)(wsb + WS_DSWZ_B) + (size_t)v * 18 * 64;
        #pragma unroll 3
        for (int i = 0; i < 9; ++i) {
            int nt = nh * 9 + i;
            bf16x8 afrag = dsw[nt * 64 + l];
            f32x4 d = {0.f, 0.f, 0.f, 0.f};
            d = __builtin_amdgcn_mfma_f32_16x16x32_bf16(afrag, abits, d, 0, 0, 0);
            // n' = nt*16 + quad*4 + r, s = mt0*16 + lc
            unsigned lo = cvtpk(elu(d[0]), elu(d[1]));
            unsigned hi = cvtpk(elu(d[2]), elu(d[3]));
            *(u32x2*)&uni[(mt0 * 16 + lc) * H1S + nt * 16 + quad * 4] = (u32x2){lo, hi};
        }
    }
    __syncthreads();

    // ---------- P1: conv2, conv-structured. Per tile q: vp(q) taps, each one
    // K=32 step: A = W2c[t] (16o x 32i), B = H1'[s][p*32..p*32+32). ----------
    f32x4 acc[4][4];           // [ti][mt]
    #pragma unroll
    for (int ti = 0; ti < 4; ++ti)
        #pragma unroll
        for (int mt = 0; mt < 4; ++mt)
            acc[ti][mt] = (f32x4){0.f, 0.f, 0.f, 0.f};
    {
        const bf16x8* w2c = (const bf16x8*)(wsb + WS_W2C_B) + (size_t)v * 9 * 64;
        unsigned qp = QPACK[w];
        #pragma unroll
        for (int ti = 0; ti < 4; ++ti) {
            int q = (qp >> (8 * ti)) & 255;
            if (q != 255) {                // wave-uniform
                int qy = q / 5, qx = q % 5;
                int py0 = qy > 2 ? qy - 2 : 0, py1 = qy < 2 ? qy : 2;
                int px0 = qx > 2 ? qx - 2 : 0, px1 = qx < 2 ? qx : 2;
                for (int py = py0; py <= py1; ++py) {
                    for (int px = px0; px <= px1; ++px) {
                        int p = py * 3 + px;
                        int t = (qy - py) * 3 + (qx - px);
                        bf16x8 af = w2c[t * 64 + l];
                        #pragma unroll
                        for (int mt = 0; mt < 4; ++mt) {
                            bf16x8 hb = *(const bf16x8*)&uni[(mt * 16 + lc) * H1S + p * 32 + quad * 8];
                            acc[ti][mt] = __builtin_amdgcn_mfma_f32_16x16x32_bf16(af, hb, acc[ti][mt], 0, 0, 0);
                        }
                    }
                }
            }
        }
    }
    __syncthreads();   // all H1 reads done before uni is reused as sH2

    // X A-frags for P4 (this wave's b-tile bt = w>>2), built in registers
    bf16x8 xf[2];
    {
        int bt = w >> 2;
        #pragma unroll
        for (int kt = 0; kt < 2; ++kt) {
            int b = bt * 16 + lc;
            const float* xb = x + (size_t)(b * 3 + v) * 49;
            union { bf16x8 h; unsigned u[4]; } xu;
            #pragma unroll
            for (int jj = 0; jj < 4; ++jj) {
                int p0 = kt * 32 + quad * 8 + jj * 2;
                float f0 = (p0 < 49) ? xb[p0] : 0.f;
                float f1 = (p0 + 1 < 49) ? xb[p0 + 1] : 0.f;
                xu.u[jj] = cvtpk(f0, f1);
            }
            xf[kt] = xu.h;
        }
    }

    // ---------- P2: bias + ELU + packed bf16 -> sH2[s][q*16+o] (b64 stores) ----------
    {
        unsigned qp = QPACK[w];
        #pragma unroll
        for (int ti = 0; ti < 4; ++ti) {
            int q = (qp >> (8 * ti)) & 255;
            if (q != 255) {
                #pragma unroll
                for (int mt = 0; mt < 4; ++mt) {
                    float vv[4];
                    #pragma unroll
                    for (int r = 0; r < 4; ++r)
                        vv[r] = elu(acc[ti][mt][r] + sB2[quad * 4 + r]);   // o = quad*4+r
                    unsigned lo = cvtpk(vv[0], vv[1]);
                    unsigned hi = cvtpk(vv[2], vv[3]);
                    *(u32x2*)&uni[(mt * 16 + lc) * H2S + q * 16 + quad * 4] = (u32x2){lo, hi};
                }
            }
        }
    }
    // wave 1: zero k-cols 400..415 of every s-row so P3's B reads are clean
    if (w == 1) {
        unsigned short* rowp = &uni[l * H2S + 400];
        *(u32x2*)&rowp[0]  = (u32x2){0u, 0u};
        *(u32x2*)&rowp[4]  = (u32x2){0u, 0u};
        *(u32x2*)&rowp[8]  = (u32x2){0u, 0u};
        *(u32x2*)&rowp[12] = (u32x2){0u, 0u};
    }
    __syncthreads();

    // ---------- P3: conv3 GEMM  m^T: D[p][s] = W3eff-frag @ H2'[s][k'] ----------
    // wave: (mt0 = w&3 s-tile, p-tiles {ph, ph+2}, ph = w>>2)
    int ph = w >> 2;
    f32x4 acc2[2];
    acc2[0] = (f32x4){0.f, 0.f, 0.f, 0.f};
    acc2[1] = (f32x4){0.f, 0.f, 0.f, 0.f};
    {
        const bf16x8* w3f = (const bf16x8*)(wsb + WS_W3SWZ_B) + (size_t)v * 13 * 4 * 64;
        for (int kt = 0; kt < 13; ++kt) {
            bf16x8 hb = *(const bf16x8*)&uni[(mt0 * 16 + lc) * H2S + kt * 32 + quad * 8];
            #pragma unroll
            for (int c = 0; c < 2; ++c) {
                int pt = ph + 2 * c;
                bf16x8 af = w3f[(kt * 4 + pt) * 64 + l];
                acc2[c] = __builtin_amdgcn_mfma_f32_16x16x32_bf16(af, hb, acc2[c], 0, 0, 0);
            }
        }
    }
    // epilogue: means (p in rows), ||m||^2 via 2-shfl reduce
    float b3v = b3p[v];
    float mv[2][4];
    #pragma unroll
    for (int c = 0; c < 2; ++c) {
        #pragma unroll
        for (int r = 0; r < 4; ++r) {
            int p = (ph + 2 * c) * 16 + quad * 4 + r;
            mv[c][r] = (p < 49) ? (acc2[c][r] + b3v) : 0.f;
        }
    }
    {
        float sq = 0.f;
        #pragma unroll
        for (int c = 0; c < 2; ++c)
            #pragma unroll
            for (int r = 0; r < 4; ++r)
                sq = fmaf(mv[c][r], mv[c][r], sq);
        sq += __shfl_xor(sq, 16, 64);
        sq += __shfl_xor(sq, 32, 64);
        if (l < 16) atomicAdd(&sMsq[mt0 * 16 + lc], sq);   // 2 waves per s-tile
    }
    __syncthreads();   // conv3 reads of uni done before reuse as sM
    #pragma unroll
    for (int c = 0; c < 2; ++c) {
        unsigned lo = cvtpk(mv[c][0], mv[c][1]);
        unsigned hi = cvtpk(mv[c][2], mv[c][3]);
        *(u32x2*)&uni[(mt0 * 16 + lc) * MS + (ph + 2 * c) * 16 + quad * 4] = (u32x2){lo, hi};
    }
    __syncthreads();

    // ---------- P4: cross = X(32x64p) @ M^T, wave: (st = w&3, bt = w>>2) ----------
    {
        int st = w & 3, bt = w >> 2;
        f32x4 acc3 = {0.f, 0.f, 0.f, 0.f};
        #pragma unroll
        for (int kt = 0; kt < 2; ++kt) {
            bf16x8 bm = *(const bf16x8*)&uni[(st * 16 + lc) * MS + kt * 32 + quad * 8];
            acc3 = __builtin_amdgcn_mfma_f32_16x16x32_bf16(xf[kt], bm, acc3, 0, 0, 0);
        }
        int s = st * 16 + lc;
        float msq = sMsq[s];
        size_t kidx = (size_t)(chunk * 64 + s) * 3 + v;
        #pragma unroll
        for (int r = 0; r < 4; ++r) {
            int b = bt * 16 + quad * 4 + r;
            out[(size_t)b * (KSTATES * 3) + kidx] = acc3[r] - 0.5f * (msq + sXsq[b]);
        }
    }
}

extern "C" void kernel_launch(void* const* d_in, const int* in_sizes, int n_in,
                              void* d_out, int out_size, void* d_ws, size_t ws_size,
                              hipStream_t stream) {
    const float* x    = (const float*)d_in[0];   // (32,3,7,7)
    const float* emb  = (const float*)d_in[1];   // (14,2,32)
    const float* linw = (const float*)d_in[2];   // (3,448,64)
    const float* linb = (const float*)d_in[3];   // (3,64)
    const float* w1   = (const float*)d_in[4];   // (3,64,32,3,3)
    const float* b1   = (const float*)d_in[5];   // (3,32)
    const float* w2   = (const float*)d_in[6];   // (3,32,16,3,3)
    const float* b2   = (const float*)d_in[7];   // (3,16)
    const float* w3   = (const float*)d_in[8];   // (3,16,1,3,3)
    const float* b3   = (const float*)d_in[9];   // (3,1)
    float* out = (float*)d_out;
    float* ws = (float*)d_ws;

    pre_kernel<<<82, 320, 0, stream>>>(emb, linw, linb, b1, w1, w2, w3, ws);
    emission_main<<<768, 512, 0, stream>>>(x, b2, b3, ws, out);
}

// Round 11
// 100.029 us; speedup vs baseline: 1.1129x; 1.0299x over previous
//
#include <hip/hip_runtime.h>
#include <math.h>

#define NVARS 14
#define EDIM 32
#define VMIX 3
#define KSTATES 16384
#define BATCH 32

// bf16 swizzled-fragment regions in ws (byte offsets):
// W2c: the 9 distinct 16(o)x32(i) weight blocks w2[i][o][ty,tx] as MFMA
// A-fragments (27KB). H1 columns tap-major (n' = p*32+i), H2 columns
// pixel-major (n' = q*16+o) so each conv2 tap is one contiguous K=32 step.
#define WS_DSWZ_B  32768                       // [V][18][64][8] bf16 = 55296 B
#define WS_W2C_B   (WS_DSWZ_B + 55296)         // [V][9][64][8]  = 27648 B
#define WS_W3SWZ_B (WS_W2C_B + 27648)          // [V][13][4][64][8] = 79872 B

// LDS strides (shorts). H1S: 148dw%32=20 -> spread banks for b128 (ok).
// H2S: 420 shorts = 210dw, 210%32=18 -> distinct banks across 16 rows;
// 64*420*2=53760B keeps total block LDS <= 54613 so 3 blocks/CU can fit.
// NOTE: do NOT raise __launch_bounds__ min-waves beyond 4 — (512,6) forced
// VGPR=40 and spilled (R5: WRITE_SIZE 24->83MB, main 33->95us).
#define H1S 296
#define H2S 420
#define MS  72

typedef __attribute__((ext_vector_type(8))) short bf16x8;
typedef __attribute__((ext_vector_type(4))) float f32x4;
typedef __attribute__((ext_vector_type(2))) unsigned int u32x2;

static __device__ inline unsigned short f2bf(float f) {
    unsigned u = __float_as_uint(f);
    u += 0x7FFFu + ((u >> 16) & 1u);   // RNE
    return (unsigned short)(u >> 16);
}
// packed RNE f32x2 -> bf16x2 (lo in bits[15:0]); bit-identical to f2bf for
// finite values, 1 VALU instr instead of ~5-10.
static __device__ inline unsigned cvtpk(float lo, float hi) {
    unsigned r;
    asm("v_cvt_pk_bf16_f32 %0, %1, %2" : "=v"(r) : "v"(lo), "v"(hi));
    return r;
}
static __device__ inline float elu(float x) {
    return x > 0.f ? x : (__expf(x) - 1.f);
}

// Per-wave conv2 output-tile q lists (q = qy*5+qx), balanced by tap count
// vp(q) = vy[qy]*vy[qx], vy=[1,2,3,2,1], Sigma vp = 81 K-steps, 8..11/wave.
// Runtime copy (for P2 store offsets); the P1 compute path is statically
// specialized per wave via switch(w) + template<int Q> (R8: makes all tap
// addresses compile-time so the compiler batch-issues loads; no div/decode).
static __device__ const unsigned QPACK[8] = {
    0xFF04000Cu,  // w0: 12,0,4
    0xFF140607u,  // w1: 7,6,20
    0xFF18080Bu,  // w2: 11,8,24
    0xFFFF100Du,  // w3: 13,16
    0xFFFF1211u,  // w4: 17,18
    0x03010E0Au,  // w5: 10,14,1,3
    0x09051602u,  // w6: 2,22,5,9
    0x1715130Fu   // w7: 15,19,21,23
};

// ---------------- pre (single kernel, role-split grid) ----------------
// blocks [0,37): W3eff fragment swizzle (9984 groups, k' = q*16+o permuted)
//                + W2c A-fragment gather (1728 groups)
// blocks [37,79): Dmat delta rows k<14 (block = (v,k)); tap-major columns
// blocks [79,82): Dmat base row k=14 + zero-fill k>=15 (block = v)
// The swizzled layout (elem j of frag (nt,l) = M[k=(l>>4)*8+j][n=nt*16+(l&15)])
// serves BOTH as MFMA B-fragment (col=n) and A-fragment (row=n) — the
// 16x16x32 A/B lane layouts are identical. main consumes these as A.
__global__ __launch_bounds__(320) void pre_kernel(const float* __restrict__ emb,
                                                  const float* __restrict__ lin_w,
                                                  const float* __restrict__ lin_b,
                                                  const float* __restrict__ b1,
                                                  const float* __restrict__ w1,
                                                  const float* __restrict__ w2,
                                                  const float* __restrict__ w3,
                                                  float* __restrict__ ws) {
    int blk = blockIdx.x;
    int tid = threadIdx.x;
    char* wsb = (char*)ws;
    unsigned short* dmat = (unsigned short*)(wsb + WS_DSWZ_B);
    __shared__ float sP[128];
    __shared__ float sQ[64];

    if (blk < 37) {
        int g2 = blk * 320 + tid;
        if (g2 < 9984) {                   // W3eff, permuted K: k' = q*16+o
            int v = g2 / 3328;
            int r = g2 % 3328;
            int kt = r / 256;
            int r2 = r % 256;
            int nt = r2 / 64, l = r2 % 64;
            int n = nt * 16 + (l & 15);    // output pixel 0..48 (else pad)
            int kbase = kt * 32 + ((l >> 4) & 3) * 8;
            float fv[8];
            #pragma unroll
            for (int j = 0; j < 8; ++j) {
                int k = kbase + j;
                float val = 0.f;
                if (k < 400 && n < 49) {
                    int q = k >> 4, o = k & 15;     // k' = q*16 + o
                    int qy = q / 5, qx = q % 5;
                    int py = n / 7, px = n % 7;
                    int ty = py - qy, tx = px - qx;
                    if (ty >= 0 && ty < 3 && tx >= 0 && tx < 3)
                        val = w3[(size_t)(v * 16 + o) * 9 + ty * 3 + tx];
                }
                fv[j] = val;
            }
            union { unsigned u[4]; bf16x8 h; } ou;
            #pragma unroll
            for (int j = 0; j < 4; ++j) ou.u[j] = cvtpk(fv[2 * j], fv[2 * j + 1]);
            *(bf16x8*)(wsb + WS_W3SWZ_B + (size_t)g2 * 16) = ou.h;
        } else if (g2 < 11712) {           // W2c: A[o=l&15][i=(l>>4)*8+j] = w2[i][o][t]
            int g = g2 - 9984;
            int v = g / 576;
            int r = g % 576;
            int t = r / 64, l = r % 64;
            int o = l & 15;
            int ibase = ((l >> 4) & 3) * 8;
            float fv[8];
            #pragma unroll
            for (int j = 0; j < 8; ++j)
                fv[j] = w2[((size_t)(v * 32 + ibase + j) * 16 + o) * 9 + t];
            union { unsigned u[4]; bf16x8 h; } ou;
            #pragma unroll
            for (int j = 0; j < 4; ++j) ou.u[j] = cvtpk(fv[2 * j], fv[2 * j + 1]);
            *(bf16x8*)(wsb + WS_W2C_B + (size_t)g * 16) = ou.h;
        }
        return;
    }

    if (blk < 79) {                        // delta row (v,k)
        int b = blk - 37;
        int v = b / 14;
        int k = b % 14;
        if (tid < 128) {                   // T columns: sP[c*64+i]
            int c = tid >> 6, i = tid & 63;
            const float* e = emb + (k * 2 + c) * EDIM;
            const float* lw = lin_w + ((size_t)v * 448 + k * 32) * 64 + i;
            float a0 = 0.f, a1 = 0.f;
            #pragma unroll
            for (int e2 = 0; e2 < 32; e2 += 2) {
                a0 = fmaf(e[e2], lw[e2 * 64], a0);
                a1 = fmaf(e[e2 + 1], lw[(e2 + 1) * 64], a1);
            }
            sP[tid] = a0 + a1;
        }
        __syncthreads();
        if (tid < 64) sQ[tid] = sP[64 + tid] - sP[tid];
        __syncthreads();
        if (tid < 288) {
            int n = tid;
            const float* w1v = w1 + (size_t)v * 64 * 288 + n;
            float a0 = 0.f, a1 = 0.f;
            #pragma unroll
            for (int i = 0; i < 64; i += 2) {
                a0 = fmaf(sQ[i], w1v[i * 288], a0);
                a1 = fmaf(sQ[i + 1], w1v[(i + 1) * 288], a1);
            }
            // tap-major column permutation: n = i*9+p -> n2 = p*32+i
            int ci = n / 9, p = n % 9;
            int n2 = p * 32 + ci;
            int nt = n2 >> 4;
            int l = (n2 & 15) | ((k >> 3) << 4);
            dmat[((size_t)(v * 18 + nt) * 64 + l) * 8 + (k & 7)] = f2bf(a0 + a1);
        }
        return;
    }

    {                                      // base row + zero-fill, block = v
        int v = blk - 79;
        // zero all k>=15 slots of this v's Dmat region
        for (int t = tid; t < 9216; t += 320) {
            int j3 = t & 7;
            int l = (t >> 3) & 63;
            int k2 = ((l >> 4) << 3) | j3;
            if (k2 >= 15) dmat[(size_t)v * 9216 + t] = 0;
        }
        if (tid < 128) {                   // partial sums of c=0 T columns
            int half = tid >> 6, i = tid & 63;
            float a0 = 0.f, a1 = 0.f;
            for (int n2 = half * 7; n2 < half * 7 + 7; ++n2) {
                const float* e = emb + (n2 * 2) * EDIM;
                const float* lw = lin_w + ((size_t)v * 448 + n2 * 32) * 64 + i;
                #pragma unroll
                for (int e2 = 0; e2 < 32; e2 += 2) {
                    a0 = fmaf(e[e2], lw[e2 * 64], a0);
                    a1 = fmaf(e[e2 + 1], lw[(e2 + 1) * 64], a1);
                }
            }
            sP[tid] = a0 + a1;
        }
        __syncthreads();
        if (tid < 64) sQ[tid] = lin_b[v * 64 + tid] + sP[tid] + sP[64 + tid];
        __syncthreads();
        if (tid < 288) {
            int n = tid;
            const float* w1v = w1 + (size_t)v * 64 * 288 + n;
            float a0 = b1[v * 32 + n / 9], a1 = 0.f;
            #pragma unroll
            for (int i = 0; i < 64; i += 2) {
                a0 = fmaf(sQ[i], w1v[i * 288], a0);
                a1 = fmaf(sQ[i + 1], w1v[(i + 1) * 288], a1);
            }
            int ci = n / 9, p = n % 9;
            int n2 = p * 32 + ci;
            int nt = n2 >> 4;
            int l = (n2 & 15) | 16;        // k=14 -> quadK 1, j 6
            dmat[((size_t)(v * 18 + nt) * 64 + l) * 8 + 6] = f2bf(a0 + a1);
        }
    }
}

// R8: statically-specialized conv2 tile. Q is compile-time -> tap set,
// p, t, and all load offsets are constants; compiler batch-issues the
// w2c/LDS loads instead of serializing per-tap dependency chains.
template<int Q>
static __device__ __forceinline__ void do_tile(const bf16x8* __restrict__ w2c,
                                               const unsigned short* __restrict__ uni,
                                               int l, int lc, int quad,
                                               f32x4 (&acc)[4]) {
    constexpr int qy = Q / 5, qx = Q % 5;
    constexpr int py0 = qy > 2 ? qy - 2 : 0, py1 = qy < 2 ? qy : 2;
    constexpr int px0 = qx > 2 ? qx - 2 : 0, px1 = qx < 2 ? qx : 2;
    #pragma unroll
    for (int py = py0; py <= py1; ++py) {
        #pragma unroll
        for (int px = px0; px <= px1; ++px) {
            const int p = py * 3 + px;
            const int t = (qy - py) * 3 + (qx - px);
            bf16x8 af = w2c[t * 64 + l];
            #pragma unroll
            for (int mt = 0; mt < 4; ++mt) {
                bf16x8 hb = *(const bf16x8*)&uni[(mt * 16 + lc) * H1S + p * 32 + quad * 8];
                acc[mt] = __builtin_amdgcn_mfma_f32_16x16x32_bf16(af, hb, acc[mt], 0, 0, 0);
            }
        }
    }
}

// ---------------- main: MFMA decoder + distance (512 threads, 8 waves) ----------------
// All GEMMs compute the TRANSPOSED output (operand swap: weight fragment = A,
// LDS [row][k] b128 read = B). C/D layout (col=lane&15, row=(lane>>4)*4+reg)
// puts each lane's 4 regs on 4 consecutive LDS shorts -> epilogues are
// 2x v_cvt_pk_bf16_f32 + 1x ds_write_b64.
// P1 is conv-structured (81 K-steps vs 225 dense), R8: static per-wave
// specialization via switch(w).
__global__ __launch_bounds__(512, 4) void emission_main(const float* __restrict__ x,
                                                        const float* __restrict__ b2,
                                                        const float* __restrict__ b3p,
                                                        const float* __restrict__ ws,
                                                        float* __restrict__ out) {
    int bid = blockIdx.x;
    // XCD swizzle: v-trio for a chunk shares bid%8 and is temporally close.
    int group = bid / 24;
    int j24 = bid % 24;
    int v = j24 >> 3;
    int chunk = group * 8 + (j24 & 7);    // states [chunk*64, chunk*64+64)
    int tid = threadIdx.x;
    int w = tid >> 6;           // wave 0..7
    int l = tid & 63;
    int quad = l >> 4;
    int lc = l & 15;
    const char* wsb = (const char*)ws;

    // union: sH1 (64 x H1S shorts) -> sH2 (64 x H2S) -> sM (64 x MS)
    __shared__ __align__(16) unsigned short uni[64 * H2S];
    __shared__ float sMsq[64];
    __shared__ float sXsq[32];
    __shared__ float sB2[16];

    // ---------- P0: small LDS prep ----------
    if (tid < 16) sB2[tid] = b2[v * 16 + tid];
    if (tid < 64) sMsq[tid] = 0.f;
    if (tid >= 64 && tid < 96) {
        int b = tid - 64;
        const float* xb = x + (size_t)(b * 3 + v) * 49;
        float s = 0.f;
        #pragma unroll
        for (int p = 0; p < 49; ++p) s = fmaf(xb[p], xb[p], s);
        sXsq[b] = s;
    }

    int mt0 = w & 3;            // this wave's s-tile for P0b/P3
    // ---------- P0b: H1'[s][n'] = ELU(bits @ Dmat); wave (mt0, nh = w>>2) ----------
    // swapped: D = mfma(DmatFrag, bits) -> rows = n' (4 consecutive per lane).
    // R8: full unroll -> all 9 global frag loads issue before the MFMA chain.
    {
        int nh = w >> 2;
        int sg = chunk * 64 + mt0 * 16 + lc;
        bf16x8 abits;                      // B operand: col s=lc, k=quad*8+j
        #pragma unroll
        for (int j = 0; j < 8; ++j) {
            int k = quad * 8 + j;
            unsigned short u = 0;
            if (k < 14) u = ((sg >> (13 - k)) & 1) ? 0x3F80 : 0;
            else if (k == 14) u = 0x3F80;
            abits[j] = (short)u;
        }
        const bf16x8* dsw = (const bf16x8*)(wsb + WS_DSWZ_B) + (size_t)v * 18 * 64;
        #pragma unroll
        for (int i = 0; i < 9; ++i) {
            int nt = nh * 9 + i;
            bf16x8 afrag = dsw[nt * 64 + l];
            f32x4 d = {0.f, 0.f, 0.f, 0.f};
            d = __builtin_amdgcn_mfma_f32_16x16x32_bf16(afrag, abits, d, 0, 0, 0);
            // n' = nt*16 + quad*4 + r, s = mt0*16 + lc
            unsigned lo = cvtpk(elu(d[0]), elu(d[1]));
            unsigned hi = cvtpk(elu(d[2]), elu(d[3]));
            *(u32x2*)&uni[(mt0 * 16 + lc) * H1S + nt * 16 + quad * 4] = (u32x2){lo, hi};
        }
    }
    __syncthreads();

    // ---------- P1: conv2, conv-structured, statically specialized ----------
    f32x4 acc[4][4];           // [ti][mt]
    #pragma unroll
    for (int ti = 0; ti < 4; ++ti)
        #pragma unroll
        for (int mt = 0; mt < 4; ++mt)
            acc[ti][mt] = (f32x4){0.f, 0.f, 0.f, 0.f};
    {
        const bf16x8* w2c = (const bf16x8*)(wsb + WS_W2C_B) + (size_t)v * 9 * 64;
        switch (w) {
        case 0: do_tile<12>(w2c, uni, l, lc, quad, acc[0]);
                do_tile<0>(w2c, uni, l, lc, quad, acc[1]);
                do_tile<4>(w2c, uni, l, lc, quad, acc[2]); break;
        case 1: do_tile<7>(w2c, uni, l, lc, quad, acc[0]);
                do_tile<6>(w2c, uni, l, lc, quad, acc[1]);
                do_tile<20>(w2c, uni, l, lc, quad, acc[2]); break;
        case 2: do_tile<11>(w2c, uni, l, lc, quad, acc[0]);
                do_tile<8>(w2c, uni, l, lc, quad, acc[1]);
                do_tile<24>(w2c, uni, l, lc, quad, acc[2]); break;
        case 3: do_tile<13>(w2c, uni, l, lc, quad, acc[0]);
                do_tile<16>(w2c, uni, l, lc, quad, acc[1]); break;
        case 4: do_tile<17>(w2c, uni, l, lc, quad, acc[0]);
                do_tile<18>(w2c, uni, l, lc, quad, acc[1]); break;
        case 5: do_tile<10>(w2c, uni, l, lc, quad, acc[0]);
                do_tile<14>(w2c, uni, l, lc, quad, acc[1]);
                do_tile<1>(w2c, uni, l, lc, quad, acc[2]);
                do_tile<3>(w2c, uni, l, lc, quad, acc[3]); break;
        case 6: do_tile<2>(w2c, uni, l, lc, quad, acc[0]);
                do_tile<22>(w2c, uni, l, lc, quad, acc[1]);
                do_tile<5>(w2c, uni, l, lc, quad, acc[2]);
                do_tile<9>(w2c, uni, l, lc, quad, acc[3]); break;
        default: do_tile<15>(w2c, uni, l, lc, quad, acc[0]);
                do_tile<19>(w2c, uni, l, lc, quad, acc[1]);
                do_tile<21>(w2c, uni, l, lc, quad, acc[2]);
                do_tile<23>(w2c, uni, l, lc, quad, acc[3]); break;
        }
    }
    __syncthreads();   // all H1 reads done before uni is reused as sH2

    // X A-frags for P4 (this wave's b-tile bt = w>>2), built in registers
    bf16x8 xf[2];
    {
        int bt = w >> 2;
        #pragma unroll
        for (int kt = 0; kt < 2; ++kt) {
            int b = bt * 16 + lc;
            const float* xb = x + (size_t)(b * 3 + v) * 49;
            union { bf16x8 h; unsigned u[4]; } xu;
            #pragma unroll
            for (int jj = 0; jj < 4; ++jj) {
                int p0 = kt * 32 + quad * 8 + jj * 2;
                float f0 = (p0 < 49) ? xb[p0] : 0.f;
                float f1 = (p0 + 1 < 49) ? xb[p0 + 1] : 0.f;
                xu.u[jj] = cvtpk(f0, f1);
            }
            xf[kt] = xu.h;
        }
    }

    // ---------- P2: bias + ELU + packed bf16 -> sH2[s][q*16+o] (b64 stores) ----------
    {
        unsigned qp = QPACK[w];
        #pragma unroll
        for (int ti = 0; ti < 4; ++ti) {
            int q = (qp >> (8 * ti)) & 255;
            if (q != 255) {
                #pragma unroll
                for (int mt = 0; mt < 4; ++mt) {
                    float vv[4];
                    #pragma unroll
                    for (int r = 0; r < 4; ++r)
                        vv[r] = elu(acc[ti][mt][r] + sB2[quad * 4 + r]);   // o = quad*4+r
                    unsigned lo = cvtpk(vv[0], vv[1]);
                    unsigned hi = cvtpk(vv[2], vv[3]);
                    *(u32x2*)&uni[(mt * 16 + lc) * H2S + q * 16 + quad * 4] = (u32x2){lo, hi};
                }
            }
        }
    }
    // wave 1: zero k-cols 400..415 of every s-row so P3's B reads are clean
    if (w == 1) {
        unsigned short* rowp = &uni[l * H2S + 400];
        *(u32x2*)&rowp[0]  = (u32x2){0u, 0u};
        *(u32x2*)&rowp[4]  = (u32x2){0u, 0u};
        *(u32x2*)&rowp[8]  = (u32x2){0u, 0u};
        *(u32x2*)&rowp[12] = (u32x2){0u, 0u};
    }
    __syncthreads();

    // ---------- P3: conv3 GEMM  m^T: D[p][s] = W3eff-frag @ H2'[s][k'] ----------
    // wave: (mt0 = w&3 s-tile, p-tiles {ph, ph+2}, ph = w>>2)
    int ph = w >> 2;
    f32x4 acc2[2];
    acc2[0] = (f32x4){0.f, 0.f, 0.f, 0.f};
    acc2[1] = (f32x4){0.f, 0.f, 0.f, 0.f};
    {
        const bf16x8* w3f = (const bf16x8*)(wsb + WS_W3SWZ_B) + (size_t)v * 13 * 4 * 64;
        for (int kt = 0; kt < 13; ++kt) {
            bf16x8 hb = *(const bf16x8*)&uni[(mt0 * 16 + lc) * H2S + kt * 32 + quad * 8];
            #pragma unroll
            for (int c = 0; c < 2; ++c) {
                int pt = ph + 2 * c;
                bf16x8 af = w3f[(kt * 4 + pt) * 64 + l];
                acc2[c] = __builtin_amdgcn_mfma_f32_16x16x32_bf16(af, hb, acc2[c], 0, 0, 0);
            }
        }
    }
    // epilogue: means (p in rows), ||m||^2 via 2-shfl reduce
    float b3v = b3p[v];
    float mv[2][4];
    #pragma unroll
    for (int c = 0; c < 2; ++c) {
        #pragma unroll
        for (int r = 0; r < 4; ++r) {
            int p = (ph + 2 * c) * 16 + quad * 4 + r;
            mv[c][r] = (p < 49) ? (acc2[c][r] + b3v) : 0.f;
        }
    }
    {
        float sq = 0.f;
        #pragma unroll
        for (int c = 0; c < 2; ++c)
            #pragma unroll
            for (int r = 0; r < 4; ++r)
                sq = fmaf(mv[c][r], mv[c][r], sq);
        sq += __shfl_xor(sq, 16, 64);
        sq += __shfl_xor(sq, 32, 64);
        if (l < 16) atomicAdd(&sMsq[mt0 * 16 + lc], sq);   // 2 waves per s-tile
    }
    __syncthreads();   // conv3 reads of uni done before reuse as sM
    #pragma unroll
    for (int c = 0; c < 2; ++c) {
        unsigned lo = cvtpk(mv[c][0], mv[c][1]);
        unsigned hi = cvtpk(mv[c][2], mv[c][3]);
        *(u32x2*)&uni[(mt0 * 16 + lc) * MS + (ph + 2 * c) * 16 + quad * 4] = (u32x2){lo, hi};
    }
    __syncthreads();

    // ---------- P4: cross = X(32x64p) @ M^T, wave: (st = w&3, bt = w>>2) ----------
    {
        int st = w & 3, bt = w >> 2;
        f32x4 acc3 = {0.f, 0.f, 0.f, 0.f};
        #pragma unroll
        for (int kt = 0; kt < 2; ++kt) {
            bf16x8 bm = *(const bf16x8*)&uni[(st * 16 + lc) * MS + kt * 32 + quad * 8];
            acc3 = __builtin_amdgcn_mfma_f32_16x16x32_bf16(xf[kt], bm, acc3, 0, 0, 0);
        }
        int s = st * 16 + lc;
        float msq = sMsq[s];
        size_t kidx = (size_t)(chunk * 64 + s) * 3 + v;
        #pragma unroll
        for (int r = 0; r < 4; ++r) {
            int b = bt * 16 + quad * 4 + r;
            out[(size_t)b * (KSTATES * 3) + kidx] = acc3[r] - 0.5f * (msq + sXsq[b]);
        }
    }
}

extern "C" void kernel_launch(void* const* d_in, const int* in_sizes, int n_in,
                              void* d_out, int out_size, void* d_ws, size_t ws_size,
                              hipStream_t stream) {
    const float* x    = (const float*)d_in[0];   // (32,3,7,7)
    const float* emb  = (const float*)d_in[1];   // (14,2,32)
    const float* linw = (const float*)d_in[2];   // (3,448,64)
    const float* linb = (const float*)d_in[3];   // (3,64)
    const float* w1   = (const float*)d_in[4];   // (3,64,32,3,3)
    const float* b1   = (const float*)d_in[5];   // (3,32)
    const float* w2   = (const float*)d_in[6];   // (3,32,16,3,3)
    const float* b2   = (const float*)d_in[7];   // (3,16)
    const float* w3   = (const float*)d_in[8];   // (3,16,1,3,3)
    const float* b3   = (const float*)d_in[9];   // (3,1)
    float* out = (float*)d_out;
    float* ws = (float*)d_ws;

    pre_kernel<<<82, 320, 0, stream>>>(emb, linw, linb, b1, w1, w2, w3, ws);
    emission_main<<<768, 512, 0, stream>>>(x, b2, b3, ws, out);
}